// Round 12
// baseline (793.500 us; speedup 1.0000x reference)
//
#include <hip/hip_runtime.h>
#include <math.h>

// Problem constants: S=512, B=256, V=100000, E=128, H=256
#define S_LEN 512
#define B_SZ  256
#define E_SZ  128
#define H_SZ  256
#define XSTP  65536  // floats per step in fragment-linear xproj layout (B*H)

typedef __attribute__((ext_vector_type(8))) short bf16x8;
typedef __attribute__((ext_vector_type(4))) float f32x4;

// W_ih pre-converted to bf16 hi/lo, fragment-linear (verified R6-R10).
__device__ short g_wfh[H_SZ * E_SZ];   // 64 KB
__device__ short g_wfl[H_SZ * E_SZ];   // 64 KB
// producer->consumer flags: one per embed tile (s,j), id = s*8+j.
__device__ int   g_flags[4096];

__device__ __forceinline__ unsigned pkbf(float a, float b) {
    unsigned r; asm("v_cvt_pk_bf16_f32 %0, %1, %2" : "=v"(r) : "v"(a), "v"(b));
    return r;
}
__device__ __forceinline__ float fromlo(unsigned u) {
    union { unsigned u; float f; } c; c.u = u << 16; return c.f;
}
__device__ __forceinline__ float fromhi(unsigned u) {
    union { unsigned u; float f; } c; c.u = u & 0xffff0000u; return c.f;
}
__device__ __forceinline__ void cvt_hilo8(float4 a, float4 b, bf16x8& hi, bf16x8& lo) {
    unsigned h0 = pkbf(a.x, a.y), h1 = pkbf(a.z, a.w);
    unsigned h2 = pkbf(b.x, b.y), h3 = pkbf(b.z, b.w);
    unsigned l0 = pkbf(a.x - fromlo(h0), a.y - fromhi(h0));
    unsigned l1 = pkbf(a.z - fromlo(h1), a.w - fromhi(h1));
    unsigned l2 = pkbf(b.x - fromlo(h2), b.y - fromhi(h2));
    unsigned l3 = pkbf(b.z - fromlo(h3), b.w - fromhi(h3));
    union { bf16x8 v; unsigned u[4]; } H, L;
    H.u[0] = h0; H.u[1] = h1; H.u[2] = h2; H.u[3] = h3;
    L.u[0] = l0; L.u[1] = l1; L.u[2] = l2; L.u[3] = l3;
    hi = H.v; lo = L.v;
}

// tanh(v) = 1 - 2/(exp2(C*v)+1). Numerics validated R4-R11.
__device__ __forceinline__ float tanhC(float v) {
    float e = __builtin_amdgcn_exp2f(v * 2.8853900818f);
    return fmaf(-2.f, __builtin_amdgcn_rcpf(e + 1.f), 1.f);
}

// coherent (agent-scope) loads: intra-kernel producer-consumer xp reads
// must bypass potentially-stale L1/L2 (no kernel boundary to invalidate).
__device__ __forceinline__ int flagld(const int* p) {
    return __hip_atomic_load(p, __ATOMIC_RELAXED, __HIP_MEMORY_SCOPE_AGENT);
}
__device__ __forceinline__ f32x4 aload4(const float* p) {
    f32x4 v;
    v[0] = __hip_atomic_load(p + 0, __ATOMIC_RELAXED, __HIP_MEMORY_SCOPE_AGENT);
    v[1] = __hip_atomic_load(p + 1, __ATOMIC_RELAXED, __HIP_MEMORY_SCOPE_AGENT);
    v[2] = __hip_atomic_load(p + 2, __ATOMIC_RELAXED, __HIP_MEMORY_SCOPE_AGENT);
    v[3] = __hip_atomic_load(p + 3, __ATOMIC_RELAXED, __HIP_MEMORY_SCOPE_AGENT);
    return v;
}

// ---------------------------------------------------------------------------
// Kernel 0: W_ih -> bf16 hi/lo fragment-linear + zero the tile flags.
// Runs stream-ordered before the fused kernel on every launch (replay-safe).
// ---------------------------------------------------------------------------
__global__ void prep_w_kernel(const float* __restrict__ W_ih) {
    const int t  = blockIdx.x * 256 + threadIdx.x;   // 0..4095
    g_flags[t] = 0;
    const int l  = t & 63;
    const int kk = (t >> 6) & 3;
    const int ht = t >> 8;
    const int h  = ht * 16 + (l & 15);
    const int k0 = kk * 32 + (l >> 4) * 8;
    const float* wp = W_ih + h * E_SZ + k0;
    float4 a = *(const float4*)wp;
    float4 b = *(const float4*)(wp + 4);
    bf16x8 hi, lo;
    cvt_hilo8(a, b, hi, lo);
    *(bf16x8*)&g_wfh[t * 8] = hi;
    *(bf16x8*)&g_wfl[t * 8] = lo;
}

// ---------------------------------------------------------------------------
// FUSED kernel: blocks 0..15 = scan role (R9/R10-verified fp32 scan, 276us),
// blocks 16..2063 = embed role (R10-verified 32-row tile x2 per block).
// Embed tile (s,j) release-stores g_flags[s*8+j]; scan block g waits only on
// j0 = g>>1 per slice, confirmed one step ahead of use (spin only if embed
// behind; embed never waits -> no deadlock possible).
// ---------------------------------------------------------------------------
__global__ __launch_bounds__(512) void fused_kernel(
    const int*   __restrict__ X,
    const float* __restrict__ emb,
    const float* __restrict__ b_ih,
    const float* __restrict__ b_hh,
    const float* __restrict__ W_hh,
    float*       __restrict__ xproj,
    float*       __restrict__ out)
{
    extern __shared__ char smem[];
    const int tid = threadIdx.x;

    if (blockIdx.x >= 16) {
        // =================== EMBED ROLE (2 tiles / block) ===================
        const int half = tid >> 8;           // 0,1
        const int tt   = tid & 255;
        const int tl   = (int)(blockIdx.x - 16) * 2 + half;   // tile 0..4095
        char*  ebase = smem + half * 16512;
        int*   toks  = (int*)ebase;
        short* BtH   = (short*)(ebase + 128);                 // 4096 shorts
        short* BtL   = BtH + 4096;

        const int wave = tt >> 6, lane = tt & 63, quad = lane >> 4;
        const size_t row0 = (size_t)tl * 32;
        const int s_idx = tl >> 3;
        const int bbase = (tl & 7) * 32;

        if (tt < 32) toks[tt] = X[row0 + tt];
        __syncthreads();

        {   // stage emb tile (hi/lo) into B-frag-linear LDS (coalesced 64B/thread)
            const int r = tt >> 3, kk = (tt >> 1) & 3, hq = tt & 1;
            const float* ep = emb + (size_t)toks[r] * E_SZ + kk * 32 + hq * 16;
            float4 a0 = ((const float4*)ep)[0];
            float4 b0 = ((const float4*)ep)[1];
            float4 a1 = ((const float4*)ep)[2];
            float4 b1 = ((const float4*)ep)[3];
            bf16x8 h0, l0, h1, l1;
            cvt_hilo8(a0, b0, h0, l0);
            cvt_hilo8(a1, b1, h1, l1);
            const int q0 = hq * 2, rl = r & 15, nt = r >> 4;
            *(bf16x8*)&BtH[((nt * 4 + kk) * 64 + q0 * 16 + rl) * 8]       = h0;
            *(bf16x8*)&BtL[((nt * 4 + kk) * 64 + q0 * 16 + rl) * 8]       = l0;
            *(bf16x8*)&BtH[((nt * 4 + kk) * 64 + (q0 + 1) * 16 + rl) * 8] = h1;
            *(bf16x8*)&BtL[((nt * 4 + kk) * 64 + (q0 + 1) * 16 + rl) * 8] = l1;
        }
        __syncthreads();

#pragma unroll
        for (int mt = 0; mt < 4; ++mt) {
            const int ht = wave * 4 + mt;
            bf16x8 wh[4], wl[4];
#pragma unroll
            for (int kk = 0; kk < 4; ++kk) {
                wh[kk] = *(const bf16x8*)&g_wfh[((ht * 4 + kk) * 64 + lane) * 8];
                wl[kk] = *(const bf16x8*)&g_wfl[((ht * 4 + kk) * 64 + lane) * 8];
            }
            f32x4 acc0 = {0.f, 0.f, 0.f, 0.f};
            f32x4 acc1 = {0.f, 0.f, 0.f, 0.f};
#pragma unroll
            for (int kk = 0; kk < 4; ++kk) {
                bf16x8 bh0  = *(const bf16x8*)&BtH[((0 * 4 + kk) * 64 + lane) * 8];
                bf16x8 blo0 = *(const bf16x8*)&BtL[((0 * 4 + kk) * 64 + lane) * 8];
                bf16x8 bh1  = *(const bf16x8*)&BtH[((1 * 4 + kk) * 64 + lane) * 8];
                bf16x8 blo1 = *(const bf16x8*)&BtL[((1 * 4 + kk) * 64 + lane) * 8];
                acc0 = __builtin_amdgcn_mfma_f32_16x16x32_bf16(wh[kk], bh0,  acc0, 0, 0, 0);
                acc0 = __builtin_amdgcn_mfma_f32_16x16x32_bf16(wh[kk], blo0, acc0, 0, 0, 0);
                acc0 = __builtin_amdgcn_mfma_f32_16x16x32_bf16(wl[kk], bh0,  acc0, 0, 0, 0);
                acc1 = __builtin_amdgcn_mfma_f32_16x16x32_bf16(wh[kk], bh1,  acc1, 0, 0, 0);
                acc1 = __builtin_amdgcn_mfma_f32_16x16x32_bf16(wh[kk], blo1, acc1, 0, 0, 0);
                acc1 = __builtin_amdgcn_mfma_f32_16x16x32_bf16(wl[kk], bh1,  acc1, 0, 0, 0);
            }
            const int hb = ht * 16 + quad * 4;
            float4 bi  = *(const float4*)&b_ih[hb];
            float4 bh4 = *(const float4*)&b_hh[hb];
#pragma unroll
            for (int nt = 0; nt < 2; ++nt) {
                const int b   = bbase + nt * 16;
                const int blk = b >> 5, str = (b >> 4) & 1;
                f32x4 o = (nt == 0) ? acc0 : acc1;
                o[0] += bi.x + bh4.x; o[1] += bi.y + bh4.y;
                o[2] += bi.z + bh4.z; o[3] += bi.w + bh4.w;
                float* dst = xproj + (size_t)s_idx * XSTP
                           + ((((blk * 2 + str) * 8 + (ht >> 1)) * 2 + (ht & 1)) * 64 + lane) * 4;
                *(f32x4*)dst = o;
            }
        }

        // publish: all threads' stores drained (syncthreads -> vmcnt(0)),
        // then L2 writeback + device-scope release store of this tile's flag.
        __syncthreads();
        if (tt == 0) {
            __threadfence();
            __hip_atomic_store(&g_flags[tl], 1, __ATOMIC_RELEASE, __HIP_MEMORY_SCOPE_AGENT);
        }
        return;
    }

    // ====================== SCAN ROLE (blocks 0..15) ======================
    short* HB0 = (short*)smem;            // 8KB state buf 0
    short* HB1 = HB0 + 4096;              // 8KB state buf 1
    float* sred = (float*)(smem + 16384); // [8][16]

    const int wave = tid >> 6;
    const int lane = tid & 63;
    const int bl   = lane & 15;
    const int quad = lane >> 4;
    const int B0   = blockIdx.x * 16;
    const int j0   = blockIdx.x >> 1;     // embed tile column this block needs
    const int* flagbase = g_flags + j0;

    bf16x8 wfrag[2][8];
#pragma unroll
    for (int mt = 0; mt < 2; ++mt) {
        const int h = wave * 32 + mt * 16 + bl;
#pragma unroll
        for (int kk = 0; kk < 8; ++kk) {
            const float* wp = W_hh + (size_t)h * H_SZ + kk * 32 + quad * 8;
            float4 a = *(const float4*)wp;
            float4 b = *(const float4*)(wp + 4);
            union { bf16x8 v; unsigned u[4]; } F;
            F.u[0] = pkbf(a.x, a.y); F.u[1] = pkbf(a.z, a.w);
            F.u[2] = pkbf(b.x, b.y); F.u[3] = pkbf(b.z, b.w);
            wfrag[mt][kk] = F.v;
        }
    }

    ((int4*)HB0)[tid] = make_int4(0, 0, 0, 0);   // zero buf0 (8KB)

    const int xsw = (bl & 8) << 2;
    const short* rd0 = HB0 + ((lane * 8) ^ xsw);
    const short* rd1 = HB1 + ((lane * 8) ^ xsw);
    const int wo = (wave * 512 + (quad >> 1) * 128 + bl * 8 + (quad & 1) * 4) ^ xsw;
    short* const w0 = HB0 + wo;
    short* const w1 = HB1 + wo;

    const float* xpb = xproj + ((size_t)blockIdx.x * 16 + wave * 2) * 256 + lane * 4;

    // wait for slices 0,1 then load initial xp (coherent)
    while (flagld(flagbase + 0 * 8) == 0) {}
    while (flagld(flagbase + 1 * 8) == 0) {}
    f32x4 xe0 = aload4(xpb);
    f32x4 xe1 = aload4(xpb + 256);
    f32x4 xo0 = aload4(xpb + XSTP);
    f32x4 xo1 = aload4(xpb + XSTP + 256);
    int f_e = flagld(flagbase + 2 * 8);   // slice 2
    int f_o = flagld(flagbase + 3 * 8);   // slice 3

    __syncthreads();

    auto do_step = [&](const short* rd, short* wr, f32x4& x0, f32x4& x1,
                       const float* pf, int& f, const int* fcur, const int* fnext) {
        bf16x8 bf[8];
#pragma unroll
        for (int kk = 0; kk < 8; ++kk)
            bf[kk] = *(const bf16x8*)(rd + kk * 512);

        f32x4 a0 = x0, b0 = {0.f,0.f,0.f,0.f};
#pragma unroll
        for (int kk = 0; kk < 4; ++kk) {
            a0 = __builtin_amdgcn_mfma_f32_16x16x32_bf16(wfrag[0][kk],   bf[kk],   a0, 0, 0, 0);
            b0 = __builtin_amdgcn_mfma_f32_16x16x32_bf16(wfrag[0][kk+4], bf[kk+4], b0, 0, 0, 0);
        }
        f32x4 a1 = x1, b1 = {0.f,0.f,0.f,0.f};
#pragma unroll
        for (int kk = 0; kk < 4; ++kk) {
            a1 = __builtin_amdgcn_mfma_f32_16x16x32_bf16(wfrag[1][kk],   bf[kk],   a1, 0, 0, 0);
            b1 = __builtin_amdgcn_mfma_f32_16x16x32_bf16(wfrag[1][kk+4], bf[kk+4], b1, 0, 0, 0);
        }

        const f32x4 d0 = a0 + b0;
        float t0 = tanhC(d0[0]), t1 = tanhC(d0[1]), t2 = tanhC(d0[2]), t3 = tanhC(d0[3]);
        *(uint2*)wr = make_uint2(pkbf(t0, t1), pkbf(t2, t3));

        const f32x4 d1 = a1 + b1;
        float u0 = tanhC(d1[0]), u1 = tanhC(d1[1]), u2 = tanhC(d1[2]), u3 = tanhC(d1[3]);
        *(uint2*)(wr + 256) = make_uint2(pkbf(u0, u1), pkbf(u2, u3));

        // confirm the producer published the slice we are about to prefetch
        // (f was loaded one step earlier -> latency hidden; spin is rare)
        if (f == 0) { do { f = flagld(fcur); } while (f == 0); }
        x0 = aload4(pf);
        x1 = aload4(pf + 256);
        f = flagld(fnext);   // flag for the slice prefetched 2 steps from now

        asm volatile("s_waitcnt lgkmcnt(0)" ::: "memory");
        __builtin_amdgcn_sched_barrier(0);
        __builtin_amdgcn_s_barrier();
    };

    const float* pf = xpb + 2 * (size_t)XSTP;
    for (int s = 0; s < 510; s += 2) {
        const int ne = (s + 4 <= 511) ? (s + 4) : 511;
        const int no = (s + 5 <= 511) ? (s + 5) : 511;
        do_step(rd0, w1, xe0, xe1, pf,        f_e, flagbase + (s + 2) * 8, flagbase + ne * 8);
        do_step(rd1, w0, xo0, xo1, pf + XSTP, f_o, flagbase + (s + 3) * 8, flagbase + no * 8);
        pf += 2 * (size_t)XSTP;
    }
    // step 510: dummy prefetch of slice 0 (flag long set; f_e holds flag[511])
    do_step(rd0, w1, xe0, xe1, xpb, f_e, flagbase + 511 * 8, flagbase + 511 * 8);

    // step 511 peeled
    float vf0[4], vf1[4];
    {
        bf16x8 bf[8];
#pragma unroll
        for (int kk = 0; kk < 8; ++kk)
            bf[kk] = *(const bf16x8*)(rd1 + kk * 512);
        f32x4 a0 = xo0, a1 = xo1;
        f32x4 b0 = {0.f,0.f,0.f,0.f}, b1 = {0.f,0.f,0.f,0.f};
#pragma unroll
        for (int kk = 0; kk < 4; ++kk) {
            a0 = __builtin_amdgcn_mfma_f32_16x16x32_bf16(wfrag[0][kk],   bf[kk],   a0, 0, 0, 0);
            a1 = __builtin_amdgcn_mfma_f32_16x16x32_bf16(wfrag[1][kk],   bf[kk],   a1, 0, 0, 0);
            b0 = __builtin_amdgcn_mfma_f32_16x16x32_bf16(wfrag[0][kk+4], bf[kk+4], b0, 0, 0, 0);
            b1 = __builtin_amdgcn_mfma_f32_16x16x32_bf16(wfrag[1][kk+4], bf[kk+4], b1, 0, 0, 0);
        }
        const f32x4 d0 = a0 + b0, d1 = a1 + b1;
#pragma unroll
        for (int r = 0; r < 4; ++r) {
            vf0[r] = tanhC(d0[r]);
            vf1[r] = tanhC(d1[r]);
        }
    }

    // ---- log_softmax over h=256 per batch row ----
    float m = fmaxf(fmaxf(fmaxf(vf0[0], vf0[1]), fmaxf(vf0[2], vf0[3])),
                    fmaxf(fmaxf(vf1[0], vf1[1]), fmaxf(vf1[2], vf1[3])));
    m = fmaxf(m, __shfl_xor(m, 16));
    m = fmaxf(m, __shfl_xor(m, 32));
    if (lane < 16) sred[wave * 16 + bl] = m;
    __syncthreads();
    float mall = sred[0 * 16 + bl];
#pragma unroll
    for (int w = 1; w < 8; ++w) mall = fmaxf(mall, sred[w * 16 + bl]);
    __syncthreads();

    float ss = 0.f;
#pragma unroll
    for (int r = 0; r < 4; ++r)
        ss += __expf(vf0[r] - mall) + __expf(vf1[r] - mall);
    ss += __shfl_xor(ss, 16);
    ss += __shfl_xor(ss, 32);
    if (lane < 16) sred[wave * 16 + bl] = ss;
    __syncthreads();
    float tot = sred[0 * 16 + bl];
#pragma unroll
    for (int w = 1; w < 8; ++w) tot += sred[w * 16 + bl];
    const float lse = mall + __logf(tot);

    f32x4 o0, o1;
#pragma unroll
    for (int r = 0; r < 4; ++r) { o0[r] = vf0[r] - lse; o1[r] = vf1[r] - lse; }
    float* op = out + (size_t)(B0 + bl) * H_SZ + wave * 32 + quad * 4;
    *(f32x4*)op        = o0;
    *(f32x4*)(op + 16) = o1;
}

// ---------------------------------------------------------------------------
extern "C" void kernel_launch(void* const* d_in, const int* in_sizes, int n_in,
                              void* d_out, int out_size, void* d_ws, size_t ws_size,
                              hipStream_t stream) {
    const int*   X    = (const int*)  d_in[0];
    const float* emb  = (const float*)d_in[1];
    const float* W_ih = (const float*)d_in[2];
    const float* W_hh = (const float*)d_in[3];
    const float* b_ih = (const float*)d_in[4];
    const float* b_hh = (const float*)d_in[5];
    float* out   = (float*)d_out;
    float* xproj = (float*)d_ws;   // S*B*H fp32 = 134.2 MB, fragment-linear

    prep_w_kernel<<<dim3(16), 256, 0, stream>>>(W_ih);
    // 16 scan blocks + 2048 embed blocks (2 tiles each), 33024 B dynamic LDS
    fused_kernel<<<dim3(16 + 2048), 512, 33024, stream>>>(
        X, emb, b_ih, b_hh, W_hh, xproj, out);
}

// Round 13
// 407.297 us; speedup vs baseline: 1.9482x; 1.9482x over previous
//
#include <hip/hip_runtime.h>
#include <math.h>

// Problem constants: S=512, B=256, V=100000, E=128, H=256
#define S_LEN 512
#define B_SZ  256
#define E_SZ  128
#define H_SZ  256
#define XSTP  65536  // floats per step in fragment-linear xproj layout (B*H)

typedef __attribute__((ext_vector_type(8))) short bf16x8;
typedef __attribute__((ext_vector_type(4))) float f32x4;

// W_ih pre-converted to bf16 hi/lo, stored in FRAGMENT-LINEAR order:
// idx = ((ht*4 + kk)*64 + lane)*8, element = W_ih[ht*16+(lane&15)][kk*32+(lane>>4)*8+j]
__device__ short g_wfh[H_SZ * E_SZ];   // 64 KB
__device__ short g_wfl[H_SZ * E_SZ];   // 64 KB

__device__ __forceinline__ unsigned pkbf(float a, float b) {
    unsigned r; asm("v_cvt_pk_bf16_f32 %0, %1, %2" : "=v"(r) : "v"(a), "v"(b));
    return r;   // lo16 = bf16(a), hi16 = bf16(b), RNE
}
__device__ __forceinline__ float fromlo(unsigned u) {
    union { unsigned u; float f; } c; c.u = u << 16; return c.f;
}
__device__ __forceinline__ float fromhi(unsigned u) {
    union { unsigned u; float f; } c; c.u = u & 0xffff0000u; return c.f;
}
__device__ __forceinline__ void cvt_hilo8(float4 a, float4 b, bf16x8& hi, bf16x8& lo) {
    unsigned h0 = pkbf(a.x, a.y), h1 = pkbf(a.z, a.w);
    unsigned h2 = pkbf(b.x, b.y), h3 = pkbf(b.z, b.w);
    unsigned l0 = pkbf(a.x - fromlo(h0), a.y - fromhi(h0));
    unsigned l1 = pkbf(a.z - fromlo(h1), a.w - fromhi(h1));
    unsigned l2 = pkbf(b.x - fromlo(h2), b.y - fromhi(h2));
    unsigned l3 = pkbf(b.z - fromlo(h3), b.w - fromhi(h3));
    union { bf16x8 v; unsigned u[4]; } H, L;
    H.u[0] = h0; H.u[1] = h1; H.u[2] = h2; H.u[3] = h3;
    L.u[0] = l0; L.u[1] = l1; L.u[2] = l2; L.u[3] = l3;
    hi = H.v; lo = L.v;
}

// tanh(v) = 1 - 2/(exp2(C*v)+1), C = 2*log2(e). Numerics validated R4-R11.
__device__ __forceinline__ float tanhC(float v) {
    float e = __builtin_amdgcn_exp2f(v * 2.8853900818f);
    return fmaf(-2.f, __builtin_amdgcn_rcpf(e + 1.f), 1.f);
}

// ---------------------------------------------------------------------------
// Kernel 0: one-time W_ih -> bf16 hi/lo in fragment-linear order. (verified)
// ---------------------------------------------------------------------------
__global__ void prep_w_kernel(const float* __restrict__ W_ih) {
    const int t  = blockIdx.x * 256 + threadIdx.x;   // 0..4095
    const int l  = t & 63;
    const int kk = (t >> 6) & 3;
    const int ht = t >> 8;                            // 0..15
    const int h  = ht * 16 + (l & 15);
    const int k0 = kk * 32 + (l >> 4) * 8;
    const float* wp = W_ih + h * E_SZ + k0;
    float4 a = *(const float4*)wp;
    float4 b = *(const float4*)(wp + 4);
    bf16x8 hi, lo;
    cvt_hilo8(a, b, hi, lo);
    *(bf16x8*)&g_wfh[t * 8] = hi;
    *(bf16x8*)&g_wfl[t * 8] = lo;
}

// ---------------------------------------------------------------------------
// Kernel 1: embed gather + projection — R7/R9-verified version (121-127us).
// Session evidence: 5 structural variants (fp32/bf16 xproj, 4 shapes, 2
// occupancies, fused producer-consumer) all land 120-157us; this is the
// best verified. Fusion (R12) regressed 2x via coherent-load serialization
// + CU contention.
// ---------------------------------------------------------------------------
__global__ __launch_bounds__(256, 2) void embed_proj_mfma(
    const int*   __restrict__ X,
    const float* __restrict__ emb,
    const float* __restrict__ b_ih,
    const float* __restrict__ b_hh,
    float*       __restrict__ xproj)
{
    __shared__ int   toks[64];
    __shared__ short BtH[4][4][64][8];   // [ntile][kk][lane][j] hi, 16KB
    __shared__ short BtL[4][4][64][8];   // lo, 16KB

    const int tid  = threadIdx.x;
    const int wave = tid >> 6;           // 0..3
    const int lane = tid & 63;
    const int bl   = lane & 15;
    const int quad = lane >> 4;
    const size_t row0 = (size_t)blockIdx.x * 64;   // rows = s*256 + b
    const int s_idx = (int)(row0 >> 8);
    const int bbase = (int)(row0 & 255);

    if (tid < 64) toks[tid] = X[row0 + tid];
    __syncthreads();

    {
        const int r  = tid >> 2;         // 0..63 row
        const int kk = tid & 3;          // k-chunk of 32
        const float* ep = emb + (size_t)toks[r] * E_SZ + kk * 32;
#pragma unroll
        for (int q = 0; q < 4; ++q) {
            float4 a = *(const float4*)(ep + q * 8);
            float4 b = *(const float4*)(ep + q * 8 + 4);
            bf16x8 fh, fl;
            cvt_hilo8(a, b, fh, fl);
            *(bf16x8*)&BtH[r >> 4][kk][q * 16 + (r & 15)][0] = fh;
            *(bf16x8*)&BtL[r >> 4][kk][q * 16 + (r & 15)][0] = fl;
        }
    }
    __syncthreads();

#pragma unroll
    for (int mp = 0; mp < 2; ++mp) {
        bf16x8 wh[2][4], wl[2][4];
#pragma unroll
        for (int i = 0; i < 2; ++i) {
            const int ht = wave * 4 + mp * 2 + i;
#pragma unroll
            for (int kk = 0; kk < 4; ++kk) {
                wh[i][kk] = *(const bf16x8*)&g_wfh[((ht * 4 + kk) * 64 + lane) * 8];
                wl[i][kk] = *(const bf16x8*)&g_wfl[((ht * 4 + kk) * 64 + lane) * 8];
            }
        }

        f32x4 acc[2][4];
#pragma unroll
        for (int i = 0; i < 2; ++i)
#pragma unroll
            for (int nt = 0; nt < 4; ++nt) acc[i][nt] = (f32x4){0.f, 0.f, 0.f, 0.f};

#pragma unroll
        for (int kk = 0; kk < 4; ++kk) {
            bf16x8 bh[4], blo[4];
#pragma unroll
            for (int nt = 0; nt < 4; ++nt) {
                bh[nt]  = *(const bf16x8*)&BtH[nt][kk][lane][0];
                blo[nt] = *(const bf16x8*)&BtL[nt][kk][lane][0];
            }
#pragma unroll
            for (int i = 0; i < 2; ++i)
#pragma unroll
                for (int nt = 0; nt < 4; ++nt) {
                    f32x4 a = acc[i][nt];
                    a = __builtin_amdgcn_mfma_f32_16x16x32_bf16(wh[i][kk], bh[nt],  a, 0, 0, 0);
                    a = __builtin_amdgcn_mfma_f32_16x16x32_bf16(wh[i][kk], blo[nt], a, 0, 0, 0);
                    a = __builtin_amdgcn_mfma_f32_16x16x32_bf16(wl[i][kk], bh[nt],  a, 0, 0, 0);
                    acc[i][nt] = a;
                }
        }

#pragma unroll
        for (int i = 0; i < 2; ++i) {
            const int ht = wave * 4 + mp * 2 + i;
            const int hb = ht * 16 + quad * 4;
            float4 bi  = *(const float4*)&b_ih[hb];
            float4 bh4 = *(const float4*)&b_hh[hb];
#pragma unroll
            for (int nt = 0; nt < 4; ++nt) {
                const int b   = bbase + nt * 16;              // + bl via lane
                const int blk = b >> 5, str = (b >> 4) & 1;
                f32x4 o = acc[i][nt];
                o[0] += bi.x + bh4.x; o[1] += bi.y + bh4.y;
                o[2] += bi.z + bh4.z; o[3] += bi.w + bh4.w;
                float* dst = xproj + (size_t)s_idx * XSTP
                           + ((((blk * 2 + str) * 8 + (ht >> 1)) * 2 + (ht & 1)) * 64 + lane) * 4;
                *(f32x4*)dst = o;
            }
        }
    }
}

// ---------------------------------------------------------------------------
// Kernel 2 (v8): R9-verified scan (276.5us). XOR bank-swizzle + grouped
// epilogue + C-init-with-xp + tanhC + fragment-linear fp32 xp reads +
// distance-2 prefetch + raw-barrier-no-vmcnt-drain.
// Structural floor: 512 serial steps x ~1360cyc; ~768cyc = 8 waves x 8
// ds_read_b128 full-K state broadcast (R3/R6: both wave-count directions
// regress), ~160 MFMA issue, rest latency/barrier tail.
// ---------------------------------------------------------------------------
__global__ __launch_bounds__(512) void rnn_scan_kernel(
    const float* __restrict__ xproj,
    const float* __restrict__ W_hh,
    float*       __restrict__ out)
{
    const int tid  = threadIdx.x;
    const int wave = tid >> 6;      // 0..7
    const int lane = tid & 63;
    const int bl   = lane & 15;
    const int quad = lane >> 4;
    const int B0   = blockIdx.x * 16;

    __shared__ short HB[2][4096];   // 2 x 8KB state buffers
    __shared__ float sred[8][16];

    bf16x8 wfrag[2][8];
#pragma unroll
    for (int mt = 0; mt < 2; ++mt) {
        const int h = wave * 32 + mt * 16 + bl;
#pragma unroll
        for (int kk = 0; kk < 8; ++kk) {
            const float* wp = W_hh + (size_t)h * H_SZ + kk * 32 + quad * 8;
            float4 a = *(const float4*)wp;
            float4 b = *(const float4*)(wp + 4);
            union { bf16x8 v; unsigned u[4]; } F;
            F.u[0] = pkbf(a.x, a.y); F.u[1] = pkbf(a.z, a.w);
            F.u[2] = pkbf(b.x, b.y); F.u[3] = pkbf(b.z, b.w);
            wfrag[mt][kk] = F.v;
        }
    }

    ((int4*)&HB[0][0])[tid] = make_int4(0, 0, 0, 0);   // zero buf0 (8KB)

    const int xsw = (bl & 8) << 2;

    const short* rd0 = &HB[0][0] + ((lane * 8) ^ xsw);
    const short* rd1 = &HB[1][0] + ((lane * 8) ^ xsw);

    // write slot: h -> shorts offset (h>>5)*512 + ((h>>3)&3)*128 + bl*8 + (h&7)
    const int wo = (wave * 512 + (quad >> 1) * 128 + bl * 8 + (quad & 1) * 4) ^ xsw;
    short* const w0 = &HB[0][0] + wo;
    short* const w1 = &HB[1][0] + wo;

    // xp base, fragment-linear (verified R7)
    const float* xpb = xproj + ((size_t)blockIdx.x * 16 + wave * 2) * 256 + lane * 4;

    // distance-2 prefetch register sets (even/odd parity)
    f32x4 xe0 = *(const f32x4*)(xpb);
    f32x4 xe1 = *(const f32x4*)(xpb + 256);
    f32x4 xo0 = *(const f32x4*)(xpb + XSTP);
    f32x4 xo1 = *(const f32x4*)(xpb + XSTP + 256);

    __syncthreads();

    auto do_step = [&](const short* rd, short* wr,
                       f32x4& x0, f32x4& x1, const float* pf) {
        bf16x8 bf[8];
#pragma unroll
        for (int kk = 0; kk < 8; ++kk)
            bf[kk] = *(const bf16x8*)(rd + kk * 512);

        // mt0's chains first, then mt1's: d0's epilogue VALU overlaps
        // mt1's MFMA completion.
        f32x4 a0 = x0, b0 = {0.f,0.f,0.f,0.f};
#pragma unroll
        for (int kk = 0; kk < 4; ++kk) {
            a0 = __builtin_amdgcn_mfma_f32_16x16x32_bf16(wfrag[0][kk],   bf[kk],   a0, 0, 0, 0);
            b0 = __builtin_amdgcn_mfma_f32_16x16x32_bf16(wfrag[0][kk+4], bf[kk+4], b0, 0, 0, 0);
        }
        f32x4 a1 = x1, b1 = {0.f,0.f,0.f,0.f};
#pragma unroll
        for (int kk = 0; kk < 4; ++kk) {
            a1 = __builtin_amdgcn_mfma_f32_16x16x32_bf16(wfrag[1][kk],   bf[kk],   a1, 0, 0, 0);
            b1 = __builtin_amdgcn_mfma_f32_16x16x32_bf16(wfrag[1][kk+4], bf[kk+4], b1, 0, 0, 0);
        }

        const f32x4 d0 = a0 + b0;
        float t0 = tanhC(d0[0]), t1 = tanhC(d0[1]), t2 = tanhC(d0[2]), t3 = tanhC(d0[3]);
        *(uint2*)wr = make_uint2(pkbf(t0, t1), pkbf(t2, t3));

        const f32x4 d1 = a1 + b1;
        float u0 = tanhC(d1[0]), u1 = tanhC(d1[1]), u2 = tanhC(d1[2]), u3 = tanhC(d1[3]);
        *(uint2*)(wr + 256) = make_uint2(pkbf(u0, u1), pkbf(u2, u3));

        // prefetch for step s+2 directly into the just-consumed registers
        x0 = *(const f32x4*)pf;
        x1 = *(const f32x4*)(pf + 256);

        // own LDS ops done -> barrier. No vmcnt drain: prefetch stays in flight.
        asm volatile("s_waitcnt lgkmcnt(0)" ::: "memory");
        __builtin_amdgcn_sched_barrier(0);
        __builtin_amdgcn_s_barrier();
    };

    const float* pf = xpb + 2 * (size_t)XSTP;
    for (int s = 0; s < 510; s += 2) {
        do_step(rd0, w1, xe0, xe1, pf);          // even step s   (pf -> s+2)
        do_step(rd1, w0, xo0, xo1, pf + XSTP);   // odd step s+1  (pf -> s+3)
        pf += 2 * (size_t)XSTP;
    }
    do_step(rd0, w1, xe0, xe1, xpb);             // step 510 (dummy in-bounds pf)

    // step 511 peeled: read buf1, keep fp32 tanh values for log_softmax
    float vf0[4], vf1[4];
    {
        bf16x8 bf[8];
#pragma unroll
        for (int kk = 0; kk < 8; ++kk)
            bf[kk] = *(const bf16x8*)(rd1 + kk * 512);
        f32x4 a0 = xo0, a1 = xo1;
        f32x4 b0 = {0.f,0.f,0.f,0.f}, b1 = {0.f,0.f,0.f,0.f};
#pragma unroll
        for (int kk = 0; kk < 4; ++kk) {
            a0 = __builtin_amdgcn_mfma_f32_16x16x32_bf16(wfrag[0][kk],   bf[kk],   a0, 0, 0, 0);
            a1 = __builtin_amdgcn_mfma_f32_16x16x32_bf16(wfrag[1][kk],   bf[kk],   a1, 0, 0, 0);
            b0 = __builtin_amdgcn_mfma_f32_16x16x32_bf16(wfrag[0][kk+4], bf[kk+4], b0, 0, 0, 0);
            b1 = __builtin_amdgcn_mfma_f32_16x16x32_bf16(wfrag[1][kk+4], bf[kk+4], b1, 0, 0, 0);
        }
        const f32x4 d0 = a0 + b0, d1 = a1 + b1;
#pragma unroll
        for (int r = 0; r < 4; ++r) {
            vf0[r] = tanhC(d0[r]);
            vf1[r] = tanhC(d1[r]);
        }
    }

    // ---- log_softmax over h=256 for each batch row bl ----
    float m = fmaxf(fmaxf(fmaxf(vf0[0], vf0[1]), fmaxf(vf0[2], vf0[3])),
                    fmaxf(fmaxf(vf1[0], vf1[1]), fmaxf(vf1[2], vf1[3])));
    m = fmaxf(m, __shfl_xor(m, 16));
    m = fmaxf(m, __shfl_xor(m, 32));
    if (lane < 16) sred[wave][bl] = m;
    __syncthreads();
    float mall = sred[0][bl];
#pragma unroll
    for (int w = 1; w < 8; ++w) mall = fmaxf(mall, sred[w][bl]);
    __syncthreads();

    float ss = 0.f;
#pragma unroll
    for (int r = 0; r < 4; ++r)
        ss += __expf(vf0[r] - mall) + __expf(vf1[r] - mall);
    ss += __shfl_xor(ss, 16);
    ss += __shfl_xor(ss, 32);
    if (lane < 16) sred[wave][bl] = ss;
    __syncthreads();
    float tot = sred[0][bl];
#pragma unroll
    for (int w = 1; w < 8; ++w) tot += sred[w][bl];
    const float lse = mall + __logf(tot);

    f32x4 o0, o1;
#pragma unroll
    for (int r = 0; r < 4; ++r) { o0[r] = vf0[r] - lse; o1[r] = vf1[r] - lse; }
    float* op = out + (size_t)(B0 + bl) * H_SZ + wave * 32 + quad * 4;
    *(f32x4*)op        = o0;
    *(f32x4*)(op + 16) = o1;
}

// ---------------------------------------------------------------------------
extern "C" void kernel_launch(void* const* d_in, const int* in_sizes, int n_in,
                              void* d_out, int out_size, void* d_ws, size_t ws_size,
                              hipStream_t stream) {
    const int*   X    = (const int*)  d_in[0];
    const float* emb  = (const float*)d_in[1];
    const float* W_ih = (const float*)d_in[2];
    const float* W_hh = (const float*)d_in[3];
    const float* b_ih = (const float*)d_in[4];
    const float* b_hh = (const float*)d_in[5];
    float* out   = (float*)d_out;
    float* xproj = (float*)d_ws;   // S*B*H fp32 = 134.2 MB, fragment-linear

    prep_w_kernel<<<dim3(16), 256, 0, stream>>>(W_ih);
    embed_proj_mfma<<<dim3((S_LEN * B_SZ) / 64), 256, 0, stream>>>(
        X, emb, b_ih, b_hh, xproj);
    rnn_scan_kernel<<<dim3(B_SZ / 16), 512, 0, stream>>>(xproj, W_hh, out);
}